// Round 13
// baseline (116.521 us; speedup 1.0000x reference)
//
#include <hip/hip_runtime.h>
#include <hip/hip_bf16.h>

#define DIM 768
#define TD 2304
#define NB 8
#define NS 4096
#define NE 6

typedef __attribute__((ext_vector_type(8))) short bf16x8;
typedef __attribute__((ext_vector_type(4))) float f32x4;

// ws layout (float offsets)
#define OFF_BPK    0        // [72 ks][2 m][64 lane][8 j] u16 = 73728 u16 = 36864 f
#define OFF_A2F    36864    // [2304][6] f32 delta-mean fold
#define OFF_CB0    50688    // [16]
#define OFF_ACCSUM 50704    // [8][6] + pad = 64
#define OFF_CONSTB 50768    // [8][6] + pad = 64
#define OFF_QP2    50832    // [2 khalf][32768][12] = 786432

__device__ __forceinline__ unsigned short f2bf(float f) {
    union { float f; unsigned u; } a; a.f = f;
    unsigned r = a.u + 0x7FFFu + ((a.u >> 16) & 1u);
    return (unsigned short)(r >> 16);
}

__device__ __forceinline__ bf16x8 pack8(float4 a, float4 b) {
    union { bf16x8 v; __hip_bfloat162 h[4]; } u;
    u.h[0] = __float22bfloat162_rn(make_float2(a.x, a.y));
    u.h[1] = __float22bfloat162_rn(make_float2(a.z, a.w));
    u.h[2] = __float22bfloat162_rn(make_float2(b.x, b.y));
    u.h[3] = __float22bfloat162_rn(make_float2(b.z, b.w));
    return u.v;
}

// ---------------- kernel B: fold coefficients into MFMA B-fragment layout ----
__global__ __launch_bounds__(256) void k_fold(
    const float* __restrict__ Wspat, const float* __restrict__ Wtemp,
    const float* __restrict__ Wsync, const float* __restrict__ Wroute,
    const float* __restrict__ Wglob, const float* __restrict__ bglob,
    const float* __restrict__ broute, const float* __restrict__ bspat,
    const float* __restrict__ btemp, const float* __restrict__ bsync,
    unsigned short* __restrict__ Bpk, float* __restrict__ A2F,
    float* __restrict__ cb0, float* __restrict__ accsum)
{
    __shared__ float lwr[288 * NE];
    __shared__ float lgf[224 * NE];
    const int t = threadIdx.x;
    for (int i = t; i < 288 * NE; i += 256) lwr[i] = Wroute[i];
    __syncthreads();
    if (t < 224) {
        float g[NE] = {0, 0, 0, 0, 0, 0};
        for (int o = 0; o < 64; ++o) {
            const float w = Wglob[t * 64 + o];
            #pragma unroll
            for (int e = 0; e < NE; ++e) g[e] += w * lwr[(224 + o) * NE + e];
        }
        #pragma unroll
        for (int e = 0; e < NE; ++e) lgf[t * NE + e] = g[e];
    }
    __syncthreads();
    if (blockIdx.x == 0) {
        if (t < NE) {
            float a = broute[t];
            for (int o = 0; o < 64; ++o)  a += bglob[o] * lwr[(224 + o) * NE + t];
            for (int o = 0; o < 128; ++o) a += bspat[o] * (lwr[o * NE + t] + lgf[o * NE + t]);
            for (int o = 0; o < 64; ++o)  a += btemp[o] * (lwr[(128 + o) * NE + t] + lgf[(128 + o) * NE + t]);
            for (int o = 0; o < 32; ++o)  a += bsync[o] * (lwr[(192 + o) * NE + t] + lgf[(192 + o) * NE + t]);
            cb0[t] = a;
        }
        if (t >= 128 && t < 192) accsum[t - 128] = 0.f;
    }

    const int d = blockIdx.x * 256 + t;          // exactly 2304 threads
    const int st = d / DIM, dd = d - st * DIM;

    float p[NE] = {0, 0, 0, 0, 0, 0}, a2[NE] = {0, 0, 0, 0, 0, 0};
    for (int o = 0; o < 64; ++o) {
        const float w = Wtemp[d * 64 + o];
        #pragma unroll
        for (int e = 0; e < NE; ++e) {
            p[e]  += w * lwr[(128 + o) * NE + e];
            a2[e] += w * lgf[(128 + o) * NE + e];
        }
    }
    float qq[NE], a1[NE];
    #pragma unroll
    for (int e = 0; e < NE; ++e) { qq[e] = p[e]; a1[e] = 0.f; }
    for (int o = 0; o < 128; ++o) {
        const float w = Wspat[d * 128 + o];
        #pragma unroll
        for (int e = 0; e < NE; ++e) {
            qq[e] += w * lwr[o * NE + e];
            a1[e] += w * lgf[o * NE + e];
        }
    }
    if (st != 0) {
        const float sg = (st == 1) ? 1.f : -1.f;
        for (int o = 0; o < 32; ++o) {
            const float w = sg * Wsync[dd * 32 + o];
            #pragma unroll
            for (int e = 0; e < NE; ++e) {
                qq[e] += w * lwr[(192 + o) * NE + e];
                a1[e] += w * lgf[(192 + o) * NE + e];
            }
        }
    }
    // B-fragment scatter: B[k][n], k=d. frag: lane = (kk>>3)*16 + n, j = kk&7.
    const int ks = d >> 5, kk = d & 31;
    const int lh = (kk >> 3) * 16, j = kk & 7;
    unsigned short* b0 = Bpk + ks * 1024 + j;          // m=0 (Q/P outs 0-11)
    unsigned short* b1 = b0 + 512;                     // m=1 (A1 outs 0-5)
    #pragma unroll
    for (int e = 0; e < NE; ++e) {
        b0[(lh + e) * 8]     = f2bf(qq[e]);
        b0[(lh + 6 + e) * 8] = f2bf(p[e]);
        b1[(lh + e) * 8]     = f2bf(a1[e]);
        A2F[d * NE + e] = a2[e];
    }
}

// ---------------- kernel C: MFMA GEMM, global_load_lds pipeline, no barriers ----
// grid = 512 row-blocks * 2 k-halves = 1024; 256 thr = 4 INDEPENDENT waves.
// Wave w owns rows rb0+w*16..+15 and stages its OWN LDS region (producer ==
// consumer -> zero __syncthreads). Per 64-col chunk: BLOAD(c) -> issue 4
// global_load_lds (width 16) for chunk c+1 -> s_waitcnt vmcnt(4) (drains
// bload(c)+stage(c), LEAVES stage(c+1) in flight) -> 4 ds_read_b128 + 8
// cvt_pk + 4 MFMA. Source pre-swizzled (u ^= (row&7)<<1, even -> 64B granules
// intact) so ds_read spreads banks.

#define GLDS(SRC, DST) \
    __builtin_amdgcn_global_load_lds((const __attribute__((address_space(1))) void*)(SRC), \
                                     (__attribute__((address_space(3))) void*)(DST), 16, 0, 0)

#define STAGE(DB, C) { \
    const int gc_ = khalf * 1152 + (C) * 64; \
    const int st_ = gc_ / DIM; \
    const float* Xp_ = (st_ == 0) ? xt : ((st_ == 1) ? xa : xv); \
    const float* base_ = Xp_ + (gc_ - st_ * DIM); \
    GLDS(base_ + soff0, &smem[(DB) * 4096 + (w * 16 + 0) * 64]); \
    GLDS(base_ + soff1, &smem[(DB) * 4096 + (w * 16 + 4) * 64]); \
    GLDS(base_ + soff2, &smem[(DB) * 4096 + (w * 16 + 8) * 64]); \
    GLDS(base_ + soff3, &smem[(DB) * 4096 + (w * 16 + 12) * 64]); }

#define BLOAD(C, B00, B01, B10, B11) { \
    const unsigned short* bp = Bpk + ((khalf * 18 + (C)) << 11) + (l << 3); \
    B00 = *(const bf16x8*)(bp); \
    B01 = *(const bf16x8*)(bp + 512); \
    B10 = *(const bf16x8*)(bp + 1024); \
    B11 = *(const bf16x8*)(bp + 1536); }

#define CMPT(DB, B00, B01, B10, B11) { \
    const float* ab_ = &smem[(DB) * 4096 + aoff]; \
    const float4 x0a = *(const float4*)(ab_ + u0f); \
    const float4 x0b = *(const float4*)(ab_ + u0f + 4); \
    const float4 x1a = *(const float4*)(ab_ + u1f); \
    const float4 x1b = *(const float4*)(ab_ + u1f + 4); \
    const bf16x8 fA0 = pack8(x0a, x0b); \
    const bf16x8 fA1 = pack8(x1a, x1b); \
    acc0 = __builtin_amdgcn_mfma_f32_16x16x32_bf16(fA0, B00, acc0, 0, 0, 0); \
    acc1 = __builtin_amdgcn_mfma_f32_16x16x32_bf16(fA0, B01, acc1, 0, 0, 0); \
    acc0 = __builtin_amdgcn_mfma_f32_16x16x32_bf16(fA1, B10, acc0, 0, 0, 0); \
    acc1 = __builtin_amdgcn_mfma_f32_16x16x32_bf16(fA1, B11, acc1, 0, 0, 0); }

__global__ __launch_bounds__(256, 4) void k_main(
    const float* __restrict__ xt, const float* __restrict__ xa, const float* __restrict__ xv,
    const unsigned short* __restrict__ Bpk, float* __restrict__ accsum,
    float* __restrict__ qp2)
{
    __shared__ float smem[2 * 64 * 64];   // 32 KB, [db][row][64]
    const int t = threadIdx.x;
    const int l = t & 63;
    const int w = t >> 6;
    const int bid = blockIdx.x;
    const int khalf = bid & 1;
    const int rblk = bid >> 1;
    const int rb0 = rblk << 6;
    const int bb = rblk >> 6;

    // staging source offsets (per-lane, loop-invariant): instr k covers rows
    // w*16+4k..+3; lane: row += (l>>4), unit u = l&15, swizzled u^((row&7)<<1)
    const int u = l & 15;
    const int rsub = l >> 4;
    const int soff0 = (rb0 + w * 16 + 0  + rsub) * DIM + (u ^ ((( 0 + rsub) & 7) << 1)) * 4;
    const int soff1 = (rb0 + w * 16 + 4  + rsub) * DIM + (u ^ ((( 4 + rsub) & 7) << 1)) * 4;
    const int soff2 = (rb0 + w * 16 + 8  + rsub) * DIM + (u ^ ((( 8 + rsub) & 7) << 1)) * 4;
    const int soff3 = (rb0 + w * 16 + 12 + rsub) * DIM + (u ^ (((12 + rsub) & 7) << 1)) * 4;

    // compute-side addresses: row = w*16 + (l&15); K-slice h2 = (l>>4)*2 units
    const int h2 = (l >> 4) * 2;
    const int swzr = ((l & 15) & 7) << 1;
    const int aoff = (w * 16 + (l & 15)) * 64;
    const int u0f = ((h2) ^ swzr) * 4;
    const int u1f = ((8 + h2) ^ swzr) * 4;

    f32x4 acc0 = {0.f, 0.f, 0.f, 0.f};
    f32x4 acc1 = {0.f, 0.f, 0.f, 0.f};
    bf16x8 B00, B01, B10, B11;

    STAGE(0, 0)

    #pragma unroll 1
    for (int c = 0; c < 17; ++c) {
        const int db = c & 1;
        BLOAD(c, B00, B01, B10, B11)
        __builtin_amdgcn_sched_barrier(0);
        STAGE(db ^ 1, c + 1)
        __builtin_amdgcn_sched_barrier(0);
        asm volatile("s_waitcnt vmcnt(4)" ::: "memory");
        __builtin_amdgcn_sched_barrier(0);
        CMPT(db, B00, B01, B10, B11)
    }
    // final chunk (17): nothing left to prefetch
    BLOAD(17, B00, B01, B10, B11)
    asm volatile("s_waitcnt vmcnt(0)" ::: "memory");
    __builtin_amdgcn_sched_barrier(0);
    CMPT(1, B00, B01, B10, B11)

    // epilogue: D layout col=lane&15, row=(lane>>4)*4+reg
    const int c_out = l & 15, rgrp = l >> 4;
    float* qph = qp2 + (size_t)khalf * ((size_t)NB * NS * 12);
    if (c_out < 12) {
        const size_t rbase = (size_t)(rb0 + w * 16 + rgrp * 4) * 12 + c_out;
        qph[rbase]      = acc0[0];
        qph[rbase + 12] = acc0[1];
        qph[rbase + 24] = acc0[2];
        qph[rbase + 36] = acc0[3];
    }
    float v = acc1[0] + acc1[1] + acc1[2] + acc1[3];
    v += __shfl_xor(v, 16, 64);
    v += __shfl_xor(v, 32, 64);
    if (rgrp == 0 && c_out < 6)
        atomicAdd(&accsum[bb * NE + c_out], v);
}

// ---------------- kernel D: per-batch global constant ----------------
__global__ __launch_bounds__(256) void k_const(
    const float* __restrict__ xt, const float* __restrict__ xa, const float* __restrict__ xv,
    const float* __restrict__ accsum, const float* __restrict__ A2F,
    const float* __restrict__ cb0, float* __restrict__ constb)
{
    const int b = blockIdx.x, t = threadIdx.x;
    float acc[NE] = {0, 0, 0, 0, 0, 0};
    for (int f = t; f < TD; f += 256) {
        const int st = f / DIM, dd = f - st * DIM;
        const float* Xp = ((st == 0) ? xt : ((st == 1) ? xa : xv)) + (size_t)b * NS * DIM;
        const float dm = Xp[(size_t)(NS - 1) * DIM + dd] - Xp[dd];
        const float* Ap = A2F + f * NE;
        #pragma unroll
        for (int e = 0; e < NE; ++e) acc[e] += dm * Ap[e];
    }
    #pragma unroll
    for (int e = 0; e < NE; ++e)
        for (int m = 1; m < 64; m <<= 1) acc[e] += __shfl_xor(acc[e], m, 64);
    __shared__ float wred[4][NE];
    if ((t & 63) == 0) {
        #pragma unroll
        for (int e = 0; e < NE; ++e) wred[t >> 6][e] = acc[e];
    }
    __syncthreads();
    if (t < NE) {
        const float inv = 1.f / 4096.f;
        const float dsum = wred[0][t] + wred[1][t] + wred[2][t] + wred[3][t];
        constb[b * NE + t] = cb0[t] + accsum[b * NE + t] * inv + dsum * inv;
    }
}

// ---------------- kernel E: combine q - shifted p + const ----------------
__global__ __launch_bounds__(256) void k_add(
    const float* __restrict__ qp2, const float* __restrict__ constb, float* __restrict__ out)
{
    const int row = blockIdx.x * 256 + threadIdx.x;   // 32768 rows exact
    const int b = row >> 12, s = row & (NS - 1);
    const int rowp = (s == 0) ? row : row - 1;
    const size_t H = (size_t)NB * NS * 12;
    const float* q0 = qp2 + (size_t)row * 12;
    const float* q1 = qp2 + H + (size_t)row * 12;
    const float* p0 = qp2 + (size_t)rowp * 12 + 6;
    const float* p1 = qp2 + H + (size_t)rowp * 12 + 6;
    float* op = out + (size_t)row * NE;
    #pragma unroll
    for (int e = 0; e < NE; ++e)
        op[e] = constb[b * NE + e] + q0[e] + q1[e] - p0[e] - p1[e];
}

extern "C" void kernel_launch(void* const* d_in, const int* in_sizes, int n_in,
                              void* d_out, int out_size, void* d_ws, size_t ws_size,
                              hipStream_t stream)
{
    const float* xt     = (const float*)d_in[0];
    const float* xa     = (const float*)d_in[1];
    const float* xv     = (const float*)d_in[2];
    const float* Wspat  = (const float*)d_in[3];
    const float* bspat  = (const float*)d_in[4];
    const float* Wtemp  = (const float*)d_in[5];
    const float* btemp  = (const float*)d_in[6];
    const float* Wsync  = (const float*)d_in[7];
    const float* bsync  = (const float*)d_in[8];
    const float* Wglob  = (const float*)d_in[9];
    const float* bglob  = (const float*)d_in[10];
    const float* Wroute = (const float*)d_in[11];
    const float* broute = (const float*)d_in[12];
    float* out = (float*)d_out;

    float* ws = (float*)d_ws;
    unsigned short* Bpk = (unsigned short*)(ws + OFF_BPK);
    float* A2F    = ws + OFF_A2F;
    float* cb0    = ws + OFF_CB0;
    float* accsum = ws + OFF_ACCSUM;
    float* constb = ws + OFF_CONSTB;
    float* qp2    = ws + OFF_QP2;

    hipMemsetAsync(Bpk, 0, 73728 * sizeof(unsigned short), stream);
    k_fold<<<9, 256, 0, stream>>>(Wspat, Wtemp, Wsync, Wroute, Wglob, bglob,
                                  broute, bspat, btemp, bsync, Bpk, A2F, cb0, accsum);
    k_main<<<1024, 256, 0, stream>>>(xt, xa, xv, Bpk, accsum, qp2);
    k_const<<<8, 256, 0, stream>>>(xt, xa, xv, accsum, A2F, cb0, constb);
    k_add<<<128, 256, 0, stream>>>(qp2, constb, out);
}